// Round 12
// baseline (219.797 us; speedup 1.0000x reference)
//
#include <hip/hip_runtime.h>
#include <hip/hip_bf16.h>

// MultiAttentionHead: B=2, T=2048, E=1024, H=16, D=64
// Inputs (fp32): x[B,T,E], Wq[H,E,D], Wk[H,E,D], Wv[H,E,D], Wo[E,E]
// Output (fp32): combined @ Wo + x   [B,T,E]
//
// r11: attn softmax fully in-register (swapped QK^T; exp'd values feed PV).
// r12-r14: KV=128 spilled -> keep per-wave state small, static indices.
// r15: XCD-bijective swizzle (FETCH 70->12MB, L2-resident) + defer-max.
// r17: 8-wave attn + permuted V (PV 8x b128 conflict-free) + exp2 softmax.
//      attn 67.8us (Mfma 32%, VALU 44%).
// r18/r19: two qkv restructures (8-wave, then m97 acc[4][4]) both NEUTRAL
//      -> non-attn time (131-141us, stable 12 rounds) is not qkv-micro-
//      structure-bound; stop restructuring invisible kernels.
// r22 (this round): attn occupancy. Grid=512 = 2 blocks/CU is the limiter
//      (LDS 36.9KB allows 4): barriers lockstep 8-wave groups; softmax
//      serial chains can't hide. -> 4-wave blocks, 64 q-rows, grid 1024
//      (8x128 XCD-bijective) = 4 independent blocks/CU; + s_setprio(1)
//      around QK/PV MFMA clusters (T5: positive exactly in this multi-
//      block-per-CU phase-diverse regime, m191). Staging per thread
//      doubles (bounded risk; clean A/B vs r17 isolates block granularity).

#define B_ 2
#define T_ 2048
#define E_ 1024
#define H_ 16
#define D_ 64
#define VTS_ 2176   // padded vt leading dim (elements)
#define LD_ 72      // LDS tile row stride (elements; 64 + 8, keeps 16B align)

typedef _Float16 h8 __attribute__((ext_vector_type(8)));
typedef _Float16 h4 __attribute__((ext_vector_type(4)));
typedef float f32x4 __attribute__((ext_vector_type(4)));

union U4 { uint4 u; h8 h; };
union V8 { uint4 u; h4 f[2]; };   // 16 bytes = 8 halves = 2 PV B-fragments

__device__ __forceinline__ float h2f(unsigned short s) {
  _Float16 h;
  __builtin_memcpy(&h, &s, 2);
  return (float)h;
}

__device__ __forceinline__ unsigned short f2h(float f) {
  _Float16 h = (_Float16)f;
  unsigned short s;
  __builtin_memcpy(&s, &h, 2);
  return s;
}

// exp2 via v_exp_f32 when available; mathematically-identical fallback.
__device__ __forceinline__ float fexp2(float x) {
#if __has_builtin(__builtin_amdgcn_exp2f)
  return __builtin_amdgcn_exp2f(x);
#else
  return __expf(x * 0.6931471805599453f);
#endif
}

// ---------------------------------------------------------------------------
// Prep 0: x fp32 -> fp16.  grid = B*T*E/1024, block=256.
// ---------------------------------------------------------------------------
__global__ __launch_bounds__(256) void cvt_x(const float* __restrict__ x,
                                             unsigned short* __restrict__ xh) {
  const size_t i = ((size_t)blockIdx.x * 256 + threadIdx.x) * 4;
  const float4 f = *(const float4*)(x + i);
  ushort4 pk;
  pk.x = f2h(f.x); pk.y = f2h(f.y); pk.z = f2h(f.z); pk.w = f2h(f.w);
  *(ushort4*)(xh + i) = pk;
}

// ---------------------------------------------------------------------------
// Prep 1: Wq/Wk/Wv [h][e][d] fp32 -> wt [p][h][d][e] fp16. grid=(16,16,3).
// Wq additionally scaled by 0.125*log2e (softmax runs in exp2 domain).
// ---------------------------------------------------------------------------
__global__ __launch_bounds__(256) void tconv_w(
    const float* __restrict__ Wq, const float* __restrict__ Wk,
    const float* __restrict__ Wv, unsigned short* __restrict__ wt) {
  __shared__ float ts[64][65];
  const int p = blockIdx.z, h = blockIdx.y;
  const float* src = ((p == 0) ? Wq : (p == 1) ? Wk : Wv) + (size_t)h * E_ * D_;
  unsigned short* dst = wt + (size_t)(p * H_ + h) * D_ * E_;
  const float scl = (p == 0) ? 0.18033688011112042f : 1.0f;  // 0.125*log2(e)
  const int r0 = blockIdx.x * 64;  // e-tile
  const int lr = threadIdx.x >> 4, lc = (threadIdx.x & 15) * 4;
#pragma unroll
  for (int it = 0; it < 4; it++) {
    const float4 f = *(const float4*)(src + (size_t)(r0 + lr + it * 16) * D_ + lc);
    ts[lr + it * 16][lc] = f.x * scl; ts[lr + it * 16][lc + 1] = f.y * scl;
    ts[lr + it * 16][lc + 2] = f.z * scl; ts[lr + it * 16][lc + 3] = f.w * scl;
  }
  __syncthreads();
#pragma unroll
  for (int it = 0; it < 4; it++) {
    const int dr = lr + it * 16;  // d
    ushort4 pk;
    pk.x = f2h(ts[lc + 0][dr]); pk.y = f2h(ts[lc + 1][dr]);
    pk.z = f2h(ts[lc + 2][dr]); pk.w = f2h(ts[lc + 3][dr]);
    *(ushort4*)(dst + (size_t)dr * E_ + r0 + lc) = pk;
  }
}

// ---------------------------------------------------------------------------
// Prep 2: Wo [e][j] fp32 -> wot [j][e] fp16. grid=(16,16).
// ---------------------------------------------------------------------------
__global__ __launch_bounds__(256) void tconv_wo(const float* __restrict__ Wo,
                                                unsigned short* __restrict__ wot) {
  __shared__ float ts[64][65];
  const int r0 = blockIdx.x * 64;  // e-tile
  const int c0 = blockIdx.y * 64;  // j-tile
  const int lr = threadIdx.x >> 4, lc = (threadIdx.x & 15) * 4;
#pragma unroll
  for (int it = 0; it < 4; it++) {
    const float4 f = *(const float4*)(Wo + (size_t)(r0 + lr + it * 16) * E_ + c0 + lc);
    ts[lr + it * 16][lc] = f.x; ts[lr + it * 16][lc + 1] = f.y;
    ts[lr + it * 16][lc + 2] = f.z; ts[lr + it * 16][lc + 3] = f.w;
  }
  __syncthreads();
#pragma unroll
  for (int it = 0; it < 4; it++) {
    const int dr = lr + it * 16;  // j within tile
    ushort4 pk;
    pk.x = f2h(ts[lc + 0][dr]); pk.y = f2h(ts[lc + 1][dr]);
    pk.z = f2h(ts[lc + 2][dr]); pk.w = f2h(ts[lc + 3][dr]);
    *(ushort4*)(wot + (size_t)(c0 + dr) * E_ + r0 + lc) = pk;
  }
}

// ---------------------------------------------------------------------------
// Kernel 1: QKV projections via MFMA (m97-shape, r19).
// grid=(B*T/256, H, 3), block=256 (4 waves). Block: 256 tokens x 64 outs.
// Wave tile 64x64 = acc[4][4]; per kk-step 4 A + 4 B b128 reads -> 16 MFMA.
// ---------------------------------------------------------------------------
__global__ __launch_bounds__(256) void qkv_mfma(
    const unsigned short* __restrict__ xh, const unsigned short* __restrict__ wt,
    unsigned short* __restrict__ qo, unsigned short* __restrict__ ko,
    unsigned short* __restrict__ vo)
{
  __shared__ unsigned short xs[256 * LD_];   // [token][e]; epilogue: repack
  __shared__ unsigned short wsb[64 * LD_];   // [d][e]

  const int tid = threadIdx.x;
  const int w = tid >> 6, lane = tid & 63;
  const int m16 = lane & 15, quad = lane >> 4;
  const int h = blockIdx.y, p = blockIdx.z;
  const int n0 = blockIdx.x * 256;           // block token base
  const unsigned short* wb = wt + (size_t)(p * H_ + h) * D_ * E_;

  const int sr = tid >> 3;          // 0..31
  const int sc = (tid & 7) * 8;     // 0,8,...,56

  f32x4 acc[4][4];
#pragma unroll
  for (int rt = 0; rt < 4; rt++)
#pragma unroll
    for (int ct = 0; ct < 4; ct++) acc[rt][ct] = (f32x4){0.f, 0.f, 0.f, 0.f};

  for (int e0 = 0; e0 < E_; e0 += 64) {
    __syncthreads();
#pragma unroll
    for (int it = 0; it < 8; it++) {
      const int row = it * 32 + sr;
      *(uint4*)(xs + row * LD_ + sc) =
          *(const uint4*)(xh + (size_t)(n0 + row) * E_ + e0 + sc);
    }
#pragma unroll
    for (int it = 0; it < 2; it++) {
      const int row = it * 32 + sr;
      *(uint4*)(wsb + row * LD_ + sc) =
          *(const uint4*)(wb + (size_t)row * E_ + e0 + sc);
    }
    __syncthreads();

#pragma unroll
    for (int kk = 0; kk < 64; kk += 32) {
      U4 af[4], bf[4];
#pragma unroll
      for (int rt = 0; rt < 4; rt++)
        af[rt].u = *(const uint4*)(xs + (w * 64 + rt * 16 + m16) * LD_ + kk + quad * 8);
#pragma unroll
      for (int ct = 0; ct < 4; ct++)
        bf[ct].u = *(const uint4*)(wsb + (ct * 16 + m16) * LD_ + kk + quad * 8);
#pragma unroll
      for (int rt = 0; rt < 4; rt++)
#pragma unroll
        for (int ct = 0; ct < 4; ct++)
          acc[rt][ct] = __builtin_amdgcn_mfma_f32_16x16x32_f16(af[rt].h, bf[ct].h, acc[rt][ct], 0, 0, 0);
    }
  }

  const int nw = n0 + w * 64;               // wave token base
  const int b  = n0 >> 11;                  // batch (256 | 2048, never straddles)
  const int t0 = nw & (T_ - 1);
  const size_t bh = (size_t)(b * H_ + h);

  if (p == 2) {
#pragma unroll
    for (int rt = 0; rt < 4; rt++)
#pragma unroll
      for (int ct = 0; ct < 4; ct++) {
        const int d = ct * 16 + m16;
        const int t = t0 + rt * 16 + quad * 4;
        ushort4 pk;
        pk.x = f2h(acc[rt][ct][0]); pk.y = f2h(acc[rt][ct][1]);
        pk.z = f2h(acc[rt][ct][2]); pk.w = f2h(acc[rt][ct][3]);
        *(ushort4*)(vo + (bh * D_ + d) * (size_t)VTS_ + t) = pk;
      }
  } else {
    unsigned short* outp = (p == 0) ? qo : ko;
    // Reuse this wave's own xs slice (rows w*64..w*64+63): wave-local.
    unsigned short* Cw = xs + w * (64 * 72);
#pragma unroll
    for (int rt = 0; rt < 4; rt++)
#pragma unroll
      for (int ct = 0; ct < 4; ct++)
#pragma unroll
        for (int r = 0; r < 4; r++)
          Cw[(rt * 16 + quad * 4 + r) * 72 + ct * 16 + m16] = f2h(acc[rt][ct][r]);
#pragma unroll
    for (int ps = 0; ps < 2; ps++) {
      const int row = (lane >> 1) + ps * 32;
      const int half = (lane & 1) * 32;
      const uint4 d0 = *(const uint4*)(Cw + row * 72 + half);
      const uint4 d1 = *(const uint4*)(Cw + row * 72 + half + 8);
      const uint4 d2 = *(const uint4*)(Cw + row * 72 + half + 16);
      const uint4 d3 = *(const uint4*)(Cw + row * 72 + half + 24);
      unsigned short* dst = outp + (bh * T_ + t0 + row) * D_ + half;
      *(uint4*)(dst)      = d0;
      *(uint4*)(dst + 8)  = d1;
      *(uint4*)(dst + 16) = d2;
      *(uint4*)(dst + 24) = d3;
    }
  }
}

// ---------------------------------------------------------------------------
// Kernel 2: MFMA flash attention (round-22).
// grid = 1024 flat (XCD-swizzled 8x128), block = 256 (4 waves = 64 q-rows).
// 4 independent blocks/CU (LDS 36.9KB x4 = 147.5KB); barriers sync only 4
// waves; s_setprio(1) around MFMA clusters (T5, phase-diverse regime).
// KV tile = 64, double-buffered; permuted V; exp2 softmax; defer-max.
// ---------------------------------------------------------------------------
__global__ __launch_bounds__(256) void attn_kernel(
    const unsigned short* __restrict__ q, const unsigned short* __restrict__ k,
    const unsigned short* __restrict__ vt, unsigned short* __restrict__ comb)
{
  __shared__ unsigned short Kt[2][64 * LD_];   // [key][d]
  __shared__ unsigned short Vt[2][64 * LD_];   // [d][key-permuted]

  const int tid  = threadIdx.x;
  const int w    = tid >> 6;          // 0..3
  const int lane = tid & 63;
  const int m16  = lane & 15;
  const int quad = lane >> 4;

  // XCD-bijective swizzle: XCD i (= flat%8) serves swz in [i*128, (i+1)*128)
  // = 4 whole (b,h) groups -> K/V/Q ~3.1MB fits that XCD's 4MB L2.
  const int flat = blockIdx.x;                   // 0..1023
  const int swz  = (flat & 7) * 128 + (flat >> 3);
  const int xq   = swz & 31;
  const int h    = (swz >> 5) & 15;
  const int b    = swz >> 9;

  const size_t bh = (size_t)(b * H_ + h);
  const int q0 = xq * 64 + w * 16;

  U4 aQ0, aQ1;
  {
    const unsigned short* qrow = q + (bh * T_ + q0 + m16) * (size_t)D_;
    aQ0.u = *(const uint4*)(qrow + quad * 8);
    aQ1.u = *(const uint4*)(qrow + 32 + quad * 8);
  }

  f32x4 o[4];
#pragma unroll
  for (int i = 0; i < 4; i++) o[i] = (f32x4){0.f, 0.f, 0.f, 0.f};
  float mrow = -1e30f;   // running max (log2 units) of q-row m16
  float lrow = 0.f;      // running denom of q-row m16

  // staging: 256 threads stage 2 K rows + 2 permuted V rows each.
  const int sr = tid >> 3;          // 0..31
  const int sc = (tid & 7) * 8;     // 0,8,...,56
  const int vdoff = ((sc >> 2) & 3) * 16 + (sc >> 4) * 4;

  const unsigned short* kp = k  + bh * (size_t)(T_ * D_)   + (size_t)sr * D_ + sc;
  const unsigned short* vp = vt + bh * (size_t)(D_ * VTS_) + (size_t)sr * VTS_ + sc;

  uint4 kr0, kr1, vr0, vr1;
  kr0 = *(const uint4*)(kp);
  kr1 = *(const uint4*)(kp + 32 * D_);
  vr0 = *(const uint4*)(vp);
  vr1 = *(const uint4*)(vp + 32 * VTS_);
  kp += 64 * D_; vp += 64;
  {
    unsigned short* kd = &Kt[0][0] + sr * LD_ + sc;
    unsigned short* vd = &Vt[0][0] + sr * LD_ + vdoff;
    *(uint4*)(kd)             = kr0;
    *(uint4*)(kd + 32 * LD_)  = kr1;
    *(uint2*)(vd)             = make_uint2(vr0.x, vr0.y);
    *(uint2*)(vd + 16)        = make_uint2(vr0.z, vr0.w);
    *(uint2*)(vd + 32 * LD_)      = make_uint2(vr1.x, vr1.y);
    *(uint2*)(vd + 32 * LD_ + 16) = make_uint2(vr1.z, vr1.w);
  }
  __syncthreads();

  const int NT = T_ / 64;
  for (int t = 0; t < NT; t++) {
    const int cur = t & 1;
    const unsigned short* Kc = &Kt[cur][0];
    const unsigned short* Vc = &Vt[cur][0];
    const bool more = (t + 1 < NT);
    if (more) {   // issue next tile a full compute early
      kr0 = *(const uint4*)(kp);
      kr1 = *(const uint4*)(kp + 32 * D_);
      vr0 = *(const uint4*)(vp);
      vr1 = *(const uint4*)(vp + 32 * VTS_);
      kp += 64 * D_; vp += 64;
    }

    f32x4 st[4];
    __builtin_amdgcn_s_setprio(1);
#pragma unroll
    for (int ct = 0; ct < 4; ct++) {
      U4 kf0, kf1;
      kf0.u = *(const uint4*)(Kc + (ct * 16 + m16) * LD_ + quad * 8);
      kf1.u = *(const uint4*)(Kc + (ct * 16 + m16) * LD_ + 32 + quad * 8);
      f32x4 z = {0.f, 0.f, 0.f, 0.f};
      z = __builtin_amdgcn_mfma_f32_16x16x32_f16(kf0.h, aQ0.h, z, 0, 0, 0);
      z = __builtin_amdgcn_mfma_f32_16x16x32_f16(kf1.h, aQ1.h, z, 0, 0, 0);
      st[ct] = z;
    }
    __builtin_amdgcn_s_setprio(0);

    const float m0 = fmaxf(fmaxf(st[0][0], st[0][1]), fmaxf(st[0][2], st[0][3]));
    const float m1 = fmaxf(fmaxf(st[1][0], st[1][1]), fmaxf(st[1][2], st[1][3]));
    const float m2 = fmaxf(fmaxf(st[2][0], st[2][1]), fmaxf(st[2][2], st[2][3]));
    const float m3 = fmaxf(fmaxf(st[3][0], st[3][1]), fmaxf(st[3][2], st[3][3]));
    float ml = fmaxf(fmaxf(m0, m1), fmaxf(m2, m3));
    ml = fmaxf(ml, __shfl_xor(ml, 16));
    ml = fmaxf(ml, __shfl_xor(ml, 32));

    // defer-max: rescale only when some row grew by > 11 bits (P <= 2^11)
    if (!__all(ml - mrow <= 11.0f)) {
      const float mn2 = fmaxf(mrow, ml);
      const float a   = fexp2(mrow - mn2);
      float al[4];
#pragma unroll
      for (int r = 0; r < 4; r++) al[r] = __shfl(a, quad * 4 + r);
#pragma unroll
      for (int i = 0; i < 4; i++)
#pragma unroll
        for (int r = 0; r < 4; r++) o[i][r] *= al[r];
      lrow *= a;
      mrow = mn2;
    }
    const float mn = mrow;

    float sl = 0.f;
    h4 pf[4];
#pragma unroll
    for (int ct = 0; ct < 4; ct++) {
      const float e0 = fexp2(st[ct][0] - mn);
      const float e1 = fexp2(st[ct][1] - mn);
      const float e2 = fexp2(st[ct][2] - mn);
      const float e3 = fexp2(st[ct][3] - mn);
      sl += (e0 + e1) + (e2 + e3);
      pf[ct] = (h4){(_Float16)e0, (_Float16)e1, (_Float16)e2, (_Float16)e3};
    }
    sl += __shfl_xor(sl, 16);
    sl += __shfl_xor(sl, 32);
    lrow += sl;

    __builtin_amdgcn_s_setprio(1);
#pragma unroll
    for (int ctd = 0; ctd < 4; ctd++) {
      const unsigned short* vrow = Vc + (ctd * 16 + m16) * LD_ + quad * 16;
      V8 va, vb;
      va.u = *(const uint4*)(vrow);
      vb.u = *(const uint4*)(vrow + 8);
      o[ctd] = __builtin_amdgcn_mfma_f32_16x16x16f16(pf[0], va.f[0], o[ctd], 0, 0, 0);
      o[ctd] = __builtin_amdgcn_mfma_f32_16x16x16f16(pf[1], va.f[1], o[ctd], 0, 0, 0);
      o[ctd] = __builtin_amdgcn_mfma_f32_16x16x16f16(pf[2], vb.f[0], o[ctd], 0, 0, 0);
      o[ctd] = __builtin_amdgcn_mfma_f32_16x16x16f16(pf[3], vb.f[1], o[ctd], 0, 0, 0);
    }
    __builtin_amdgcn_s_setprio(0);

    if (more) {
      __syncthreads();
      unsigned short* kd = &Kt[cur ^ 1][0] + sr * LD_ + sc;
      unsigned short* vd = &Vt[cur ^ 1][0] + sr * LD_ + vdoff;
      *(uint4*)(kd)             = kr0;
      *(uint4*)(kd + 32 * LD_)  = kr1;
      *(uint2*)(vd)             = make_uint2(vr0.x, vr0.y);
      *(uint2*)(vd + 16)        = make_uint2(vr0.z, vr0.w);
      *(uint2*)(vd + 32 * LD_)      = make_uint2(vr1.x, vr1.y);
      *(uint2*)(vd + 32 * LD_ + 16) = make_uint2(vr1.z, vr1.w);
      __syncthreads();
    }
  }

  float linv[4];
#pragma unroll
  for (int r = 0; r < 4; r++) linv[r] = 1.f / __shfl(lrow, quad * 4 + r);

#pragma unroll
  for (int r = 0; r < 4; r++) {
    const int tq = q0 + quad * 4 + r;
    unsigned short* dst = comb + ((size_t)b * T_ + tq) * E_ + h * D_;
    dst[m16]      = f2h(o[0][r] * linv[r]);
    dst[16 + m16] = f2h(o[1][r] * linv[r]);
    dst[32 + m16] = f2h(o[2][r] * linv[r]);
    dst[48 + m16] = f2h(o[3][r] * linv[r]);
  }
}

// ---------------------------------------------------------------------------
// Kernel 3: out = comb @ Wo + x, coalesced LDS staging.
// grid=(B*T/128, E/64), block=256 (4 waves). Block: 128 n x 64 j.
// ---------------------------------------------------------------------------
__global__ __launch_bounds__(256) void out_mfma(
    const unsigned short* __restrict__ comb, const unsigned short* __restrict__ wot,
    const float* __restrict__ x, float* __restrict__ out)
{
  __shared__ unsigned short cs[128 * LD_];   // [n][e]
  __shared__ unsigned short wsb[64 * LD_];   // [j][e]

  const int tid = threadIdx.x;
  const int w = tid >> 6, lane = tid & 63;
  const int m16 = lane & 15, quad = lane >> 4;
  const int n0 = blockIdx.x * 128;
  const int j0 = blockIdx.y * 64;

  const int sr = tid >> 3;          // 0..31
  const int sc = (tid & 7) * 8;     // 0,8,...,56

  f32x4 acc[2][4];
#pragma unroll
  for (int rt = 0; rt < 2; rt++)
#pragma unroll
    for (int ct = 0; ct < 4; ct++) acc[rt][ct] = (f32x4){0.f, 0.f, 0.f, 0.f};

  for (int e0 = 0; e0 < E_; e0 += 64) {
    __syncthreads();
#pragma unroll
    for (int it = 0; it < 4; it++) {
      const int row = it * 32 + sr;
      *(uint4*)(cs + row * LD_ + sc) =
          *(const uint4*)(comb + (size_t)(n0 + row) * E_ + e0 + sc);
    }
#pragma unroll
    for (int it = 0; it < 2; it++) {
      const int row = it * 32 + sr;
      *(uint4*)(wsb + row * LD_ + sc) =
          *(const uint4*)(wot + (size_t)(j0 + row) * E_ + e0 + sc);
    }
    __syncthreads();

#pragma unroll
    for (int kk = 0; kk < 64; kk += 32) {
      U4 a0, a1, bf[4];
      a0.u = *(const uint4*)(cs + (w * 32 + m16) * LD_ + kk + quad * 8);
      a1.u = *(const uint4*)(cs + (w * 32 + 16 + m16) * LD_ + kk + quad * 8);
#pragma unroll
      for (int ct = 0; ct < 4; ct++)
        bf[ct].u = *(const uint4*)(wsb + (ct * 16 + m16) * LD_ + kk + quad * 8);
#pragma unroll
      for (int ct = 0; ct < 4; ct++) {
        acc[0][ct] = __builtin_amdgcn_mfma_f32_16x16x32_f16(a0.h, bf[ct].h, acc[0][ct], 0, 0, 0);
        acc[1][ct] = __builtin_amdgcn_mfma_f32_16x16x32_f16(a1.h, bf[ct].h, acc[1][ct], 0, 0, 0);
      }
    }
  }

  const int nw = n0 + w * 32;
#pragma unroll
  for (int rt = 0; rt < 2; rt++)
#pragma unroll
    for (int r = 0; r < 4; r++) {
      const int n = nw + rt * 16 + quad * 4 + r;
      const float* xr = x + (size_t)n * E_ + j0;
      float* orow = out + (size_t)n * E_ + j0;
#pragma unroll
      for (int ct = 0; ct < 4; ct++) {
        const int j = ct * 16 + m16;
        orow[j] = acc[rt][ct][r] + xr[j];
      }
    }
}

// ---------------------------------------------------------------------------
extern "C" void kernel_launch(void* const* d_in, const int* in_sizes, int n_in,
                              void* d_out, int out_size, void* d_ws, size_t ws_size,
                              hipStream_t stream) {
  (void)in_sizes; (void)n_in; (void)out_size; (void)ws_size;

  const float* x  = (const float*)d_in[0];
  const float* Wq = (const float*)d_in[1];
  const float* Wk = (const float*)d_in[2];
  const float* Wv = (const float*)d_in[3];
  const float* Wo = (const float*)d_in[4];
  float* out = (float*)d_out;

  unsigned short* ws0  = (unsigned short*)d_ws;
  unsigned short* xh   = ws0;                    // 4M elems (aliases comb)
  unsigned short* wt   = ws0 + 4194304;          // 3M
  unsigned short* wot  = ws0 + 7340032;          // 1M
  unsigned short* qh   = ws0 + 8388608;          // 4M
  unsigned short* kh   = ws0 + 12582912;         // 4M
  unsigned short* vth  = ws0 + 16777216;         // 32*64*2176 = 4.46M (padded)
  unsigned short* comb = xh;                     // alias: xh dead after qkv

  cvt_x<<<dim3(B_ * T_ * E_ / 1024), dim3(256), 0, stream>>>(x, xh);
  tconv_w<<<dim3(E_ / 64, H_, 3), dim3(256), 0, stream>>>(Wq, Wk, Wv, wt);
  tconv_wo<<<dim3(E_ / 64, E_ / 64), dim3(256), 0, stream>>>(Wo, wot);

  qkv_mfma<<<dim3(B_ * T_ / 256, H_, 3), dim3(256), 0, stream>>>(xh, wt, qh, kh, vth);

  attn_kernel<<<dim3(B_ * H_ * (T_ / 64)), dim3(256), 0, stream>>>(qh, kh, vth, comb);

  out_mfma<<<dim3(B_ * T_ / 128, E_ / 64), dim3(256), 0, stream>>>(comb, wot, x, out);
}

// Round 13
// 208.410 us; speedup vs baseline: 1.0546x; 1.0546x over previous
//
#include <hip/hip_runtime.h>
#include <hip/hip_bf16.h>

// MultiAttentionHead: B=2, T=2048, E=1024, H=16, D=64
// Inputs (fp32): x[B,T,E], Wq[H,E,D], Wk[H,E,D], Wv[H,E,D], Wo[E,E]
// Output (fp32): combined @ Wo + x   [B,T,E]
//
// r11: attn softmax fully in-register (swapped QK^T; exp'd values feed PV).
// r12-r14: KV=128 spilled -> keep per-wave state small, static indices.
// r15: XCD-bijective swizzle (FETCH 70->12MB, L2-resident) + defer-max.
// r17: 8-wave attn + permuted V (PV 8x b128 conflict-free) + exp2 softmax.
//      attn 66-68us (Mfma 32%, VALU 44%). BEST attn config.
// r18/r19: two qkv restructures both NEUTRAL -> non-attn (~139us stable)
//      is not qkv-micro-structure-bound.
// r22: 4-wave attn blocks REGRESSED (76us: occupancy unchanged at 34%,
//      VALU +11 from doubled staging). Reverted to 8-wave here.
// r23 (this round): launch-count elimination. Fuse the three prep kernels
//      into ONE flat-grid kernel (5120 blocks: 4096 cvt_x + 768 tconv_w +
//      256 tconv_wo; branch at block granularity). 6 launches -> 4.
//      attn = r17/r8 8-wave verbatim; qkv = m97 shape (r19); out unchanged.

#define B_ 2
#define T_ 2048
#define E_ 1024
#define H_ 16
#define D_ 64
#define VTS_ 2176   // padded vt leading dim (elements)
#define LD_ 72      // LDS tile row stride (elements; 64 + 8, keeps 16B align)

typedef _Float16 h8 __attribute__((ext_vector_type(8)));
typedef _Float16 h4 __attribute__((ext_vector_type(4)));
typedef float f32x4 __attribute__((ext_vector_type(4)));

union U4 { uint4 u; h8 h; };
union V8 { uint4 u; h4 f[2]; };   // 16 bytes = 8 halves = 2 PV B-fragments

__device__ __forceinline__ float h2f(unsigned short s) {
  _Float16 h;
  __builtin_memcpy(&h, &s, 2);
  return (float)h;
}

__device__ __forceinline__ unsigned short f2h(float f) {
  _Float16 h = (_Float16)f;
  unsigned short s;
  __builtin_memcpy(&s, &h, 2);
  return s;
}

// exp2 via v_exp_f32 when available; mathematically-identical fallback.
__device__ __forceinline__ float fexp2(float x) {
#if __has_builtin(__builtin_amdgcn_exp2f)
  return __builtin_amdgcn_exp2f(x);
#else
  return __expf(x * 0.6931471805599453f);
#endif
}

// ---------------------------------------------------------------------------
// Fused prep: grid = 5120 flat, block = 256.
//   bid <  4096 : x fp32 -> fp16 (1024 elems/block)
//   4096..4863  : Wq/Wk/Wv [h][e][d] -> wt [p][h][d][e] fp16 (Wq pre-scaled
//                 by 0.125*log2e; softmax runs in exp2 domain)
//   4864..5119  : Wo [e][j] -> wot [j][e] fp16
// ---------------------------------------------------------------------------
__global__ __launch_bounds__(256) void prep_fused(
    const float* __restrict__ x,  unsigned short* __restrict__ xh,
    const float* __restrict__ Wq, const float* __restrict__ Wk,
    const float* __restrict__ Wv, unsigned short* __restrict__ wt,
    const float* __restrict__ Wo, unsigned short* __restrict__ wot)
{
  __shared__ float ts[64][65];
  const int bid = blockIdx.x;
  const int tid = threadIdx.x;

  if (bid < 4096) {                    // ---- cvt_x ----
    const size_t i = ((size_t)bid * 256 + tid) * 4;
    const float4 f = *(const float4*)(x + i);
    ushort4 pk;
    pk.x = f2h(f.x); pk.y = f2h(f.y); pk.z = f2h(f.z); pk.w = f2h(f.w);
    *(ushort4*)(xh + i) = pk;
    return;
  }

  const int lr = tid >> 4, lc = (tid & 15) * 4;

  if (bid < 4096 + 768) {              // ---- tconv_w ----
    const int idx = bid - 4096;        // 768 = 16 e-tiles x 16 h x 3 p
    const int et = idx & 15, h = (idx >> 4) & 15, p = idx >> 8;
    const float* src = ((p == 0) ? Wq : (p == 1) ? Wk : Wv) + (size_t)h * E_ * D_;
    unsigned short* dst = wt + (size_t)(p * H_ + h) * D_ * E_;
    const float scl = (p == 0) ? 0.18033688011112042f : 1.0f;  // 0.125*log2(e)
    const int r0 = et * 64;            // e-tile
#pragma unroll
    for (int it = 0; it < 4; it++) {
      const float4 f = *(const float4*)(src + (size_t)(r0 + lr + it * 16) * D_ + lc);
      ts[lr + it * 16][lc] = f.x * scl; ts[lr + it * 16][lc + 1] = f.y * scl;
      ts[lr + it * 16][lc + 2] = f.z * scl; ts[lr + it * 16][lc + 3] = f.w * scl;
    }
    __syncthreads();
#pragma unroll
    for (int it = 0; it < 4; it++) {
      const int dr = lr + it * 16;     // d
      ushort4 pk;
      pk.x = f2h(ts[lc + 0][dr]); pk.y = f2h(ts[lc + 1][dr]);
      pk.z = f2h(ts[lc + 2][dr]); pk.w = f2h(ts[lc + 3][dr]);
      *(ushort4*)(dst + (size_t)dr * E_ + r0 + lc) = pk;
    }
    return;
  }

  {                                    // ---- tconv_wo ----
    const int idx = bid - 4096 - 768;  // 256 = 16 x 16
    const int r0 = (idx & 15) * 64;    // e-tile
    const int c0 = (idx >> 4) * 64;    // j-tile
#pragma unroll
    for (int it = 0; it < 4; it++) {
      const float4 f = *(const float4*)(Wo + (size_t)(r0 + lr + it * 16) * E_ + c0 + lc);
      ts[lr + it * 16][lc] = f.x; ts[lr + it * 16][lc + 1] = f.y;
      ts[lr + it * 16][lc + 2] = f.z; ts[lr + it * 16][lc + 3] = f.w;
    }
    __syncthreads();
#pragma unroll
    for (int it = 0; it < 4; it++) {
      const int dr = lr + it * 16;     // j within tile
      ushort4 pk;
      pk.x = f2h(ts[lc + 0][dr]); pk.y = f2h(ts[lc + 1][dr]);
      pk.z = f2h(ts[lc + 2][dr]); pk.w = f2h(ts[lc + 3][dr]);
      *(ushort4*)(wot + (size_t)(c0 + dr) * E_ + r0 + lc) = pk;
    }
  }
}

// ---------------------------------------------------------------------------
// Kernel 1: QKV projections via MFMA (m97-shape, r19).
// grid=(B*T/256, H, 3), block=256 (4 waves). Block: 256 tokens x 64 outs.
// Wave tile 64x64 = acc[4][4]; per kk-step 4 A + 4 B b128 reads -> 16 MFMA.
// ---------------------------------------------------------------------------
__global__ __launch_bounds__(256) void qkv_mfma(
    const unsigned short* __restrict__ xh, const unsigned short* __restrict__ wt,
    unsigned short* __restrict__ qo, unsigned short* __restrict__ ko,
    unsigned short* __restrict__ vo)
{
  __shared__ unsigned short xs[256 * LD_];   // [token][e]; epilogue: repack
  __shared__ unsigned short wsb[64 * LD_];   // [d][e]

  const int tid = threadIdx.x;
  const int w = tid >> 6, lane = tid & 63;
  const int m16 = lane & 15, quad = lane >> 4;
  const int h = blockIdx.y, p = blockIdx.z;
  const int n0 = blockIdx.x * 256;           // block token base
  const unsigned short* wb = wt + (size_t)(p * H_ + h) * D_ * E_;

  const int sr = tid >> 3;          // 0..31
  const int sc = (tid & 7) * 8;     // 0,8,...,56

  f32x4 acc[4][4];
#pragma unroll
  for (int rt = 0; rt < 4; rt++)
#pragma unroll
    for (int ct = 0; ct < 4; ct++) acc[rt][ct] = (f32x4){0.f, 0.f, 0.f, 0.f};

  for (int e0 = 0; e0 < E_; e0 += 64) {
    __syncthreads();
#pragma unroll
    for (int it = 0; it < 8; it++) {
      const int row = it * 32 + sr;
      *(uint4*)(xs + row * LD_ + sc) =
          *(const uint4*)(xh + (size_t)(n0 + row) * E_ + e0 + sc);
    }
#pragma unroll
    for (int it = 0; it < 2; it++) {
      const int row = it * 32 + sr;
      *(uint4*)(wsb + row * LD_ + sc) =
          *(const uint4*)(wb + (size_t)row * E_ + e0 + sc);
    }
    __syncthreads();

#pragma unroll
    for (int kk = 0; kk < 64; kk += 32) {
      U4 af[4], bf[4];
#pragma unroll
      for (int rt = 0; rt < 4; rt++)
        af[rt].u = *(const uint4*)(xs + (w * 64 + rt * 16 + m16) * LD_ + kk + quad * 8);
#pragma unroll
      for (int ct = 0; ct < 4; ct++)
        bf[ct].u = *(const uint4*)(wsb + (ct * 16 + m16) * LD_ + kk + quad * 8);
#pragma unroll
      for (int rt = 0; rt < 4; rt++)
#pragma unroll
        for (int ct = 0; ct < 4; ct++)
          acc[rt][ct] = __builtin_amdgcn_mfma_f32_16x16x32_f16(af[rt].h, bf[ct].h, acc[rt][ct], 0, 0, 0);
    }
  }

  const int nw = n0 + w * 64;               // wave token base
  const int b  = n0 >> 11;                  // batch (256 | 2048, never straddles)
  const int t0 = nw & (T_ - 1);
  const size_t bh = (size_t)(b * H_ + h);

  if (p == 2) {
#pragma unroll
    for (int rt = 0; rt < 4; rt++)
#pragma unroll
      for (int ct = 0; ct < 4; ct++) {
        const int d = ct * 16 + m16;
        const int t = t0 + rt * 16 + quad * 4;
        ushort4 pk;
        pk.x = f2h(acc[rt][ct][0]); pk.y = f2h(acc[rt][ct][1]);
        pk.z = f2h(acc[rt][ct][2]); pk.w = f2h(acc[rt][ct][3]);
        *(ushort4*)(vo + (bh * D_ + d) * (size_t)VTS_ + t) = pk;
      }
  } else {
    unsigned short* outp = (p == 0) ? qo : ko;
    // Reuse this wave's own xs slice (rows w*64..w*64+63): wave-local.
    unsigned short* Cw = xs + w * (64 * 72);
#pragma unroll
    for (int rt = 0; rt < 4; rt++)
#pragma unroll
      for (int ct = 0; ct < 4; ct++)
#pragma unroll
        for (int r = 0; r < 4; r++)
          Cw[(rt * 16 + quad * 4 + r) * 72 + ct * 16 + m16] = f2h(acc[rt][ct][r]);
#pragma unroll
    for (int ps = 0; ps < 2; ps++) {
      const int row = (lane >> 1) + ps * 32;
      const int half = (lane & 1) * 32;
      const uint4 d0 = *(const uint4*)(Cw + row * 72 + half);
      const uint4 d1 = *(const uint4*)(Cw + row * 72 + half + 8);
      const uint4 d2 = *(const uint4*)(Cw + row * 72 + half + 16);
      const uint4 d3 = *(const uint4*)(Cw + row * 72 + half + 24);
      unsigned short* dst = outp + (bh * T_ + t0 + row) * D_ + half;
      *(uint4*)(dst)      = d0;
      *(uint4*)(dst + 8)  = d1;
      *(uint4*)(dst + 16) = d2;
      *(uint4*)(dst + 24) = d3;
    }
  }
}

// ---------------------------------------------------------------------------
// Kernel 2: MFMA flash attention (r17/r8 8-wave, best measured: 66.3us).
// grid = 512 flat (XCD-swizzled), block = 512 (8 waves = 8 Q-tiles of 16).
// KV tile = 64, LDS double-buffered; permuted V (PV 8x b128 conflict-free);
// exp2 softmax (scale folded into Wq); defer-max THR=11 bits.
// ---------------------------------------------------------------------------
__global__ __launch_bounds__(512) void attn_kernel(
    const unsigned short* __restrict__ q, const unsigned short* __restrict__ k,
    const unsigned short* __restrict__ vt, unsigned short* __restrict__ comb)
{
  __shared__ unsigned short Kt[2][64 * LD_];   // [key][d]
  __shared__ unsigned short Vt[2][64 * LD_];   // [d][key-permuted]

  const int tid  = threadIdx.x;
  const int w    = tid >> 6;          // 0..7
  const int lane = tid & 63;
  const int m16  = lane & 15;
  const int quad = lane >> 4;

  const int flat = blockIdx.x;                   // 0..511
  const int swz  = (flat & 7) * 64 + (flat >> 3);
  const int xq   = swz & 15;
  const int h    = (swz >> 4) & 15;
  const int b    = swz >> 8;

  const size_t bh = (size_t)(b * H_ + h);
  const int q0 = xq * 128 + w * 16;

  U4 aQ0, aQ1;
  {
    const unsigned short* qrow = q + (bh * T_ + q0 + m16) * (size_t)D_;
    aQ0.u = *(const uint4*)(qrow + quad * 8);
    aQ1.u = *(const uint4*)(qrow + 32 + quad * 8);
  }

  f32x4 o[4];
#pragma unroll
  for (int i = 0; i < 4; i++) o[i] = (f32x4){0.f, 0.f, 0.f, 0.f};
  float mrow = -1e30f;   // running max (log2 units) of q-row m16
  float lrow = 0.f;      // running denom of q-row m16

  const int sr = tid >> 3;          // 0..63
  const int sc = (tid & 7) * 8;     // 0,8,...,56
  const int vdoff = ((sc >> 2) & 3) * 16 + (sc >> 4) * 4;

  const unsigned short* kp = k  + bh * (size_t)(T_ * D_)   + (size_t)sr * D_ + sc;
  const unsigned short* vp = vt + bh * (size_t)(D_ * VTS_) + (size_t)sr * VTS_ + sc;

  uint4 kr, vr;
  kr = *(const uint4*)(kp);
  vr = *(const uint4*)(vp);
  kp += 64 * D_; vp += 64;
  {
    unsigned short* kd = &Kt[0][0] + sr * LD_ + sc;
    unsigned short* vd = &Vt[0][0] + sr * LD_ + vdoff;
    *(uint4*)(kd) = kr;
    *(uint2*)(vd)      = make_uint2(vr.x, vr.y);
    *(uint2*)(vd + 16) = make_uint2(vr.z, vr.w);
  }
  __syncthreads();

  const int NT = T_ / 64;
  for (int t = 0; t < NT; t++) {
    const int cur = t & 1;
    const unsigned short* Kc = &Kt[cur][0];
    const unsigned short* Vc = &Vt[cur][0];
    const bool more = (t + 1 < NT);
    if (more) {   // issue next tile a full compute early
      kr = *(const uint4*)(kp);
      vr = *(const uint4*)(vp);
      kp += 64 * D_; vp += 64;
    }

    f32x4 st[4];
#pragma unroll
    for (int ct = 0; ct < 4; ct++) {
      U4 kf0, kf1;
      kf0.u = *(const uint4*)(Kc + (ct * 16 + m16) * LD_ + quad * 8);
      kf1.u = *(const uint4*)(Kc + (ct * 16 + m16) * LD_ + 32 + quad * 8);
      f32x4 z = {0.f, 0.f, 0.f, 0.f};
      z = __builtin_amdgcn_mfma_f32_16x16x32_f16(kf0.h, aQ0.h, z, 0, 0, 0);
      z = __builtin_amdgcn_mfma_f32_16x16x32_f16(kf1.h, aQ1.h, z, 0, 0, 0);
      st[ct] = z;
    }

    const float m0 = fmaxf(fmaxf(st[0][0], st[0][1]), fmaxf(st[0][2], st[0][3]));
    const float m1 = fmaxf(fmaxf(st[1][0], st[1][1]), fmaxf(st[1][2], st[1][3]));
    const float m2 = fmaxf(fmaxf(st[2][0], st[2][1]), fmaxf(st[2][2], st[2][3]));
    const float m3 = fmaxf(fmaxf(st[3][0], st[3][1]), fmaxf(st[3][2], st[3][3]));
    float ml = fmaxf(fmaxf(m0, m1), fmaxf(m2, m3));
    ml = fmaxf(ml, __shfl_xor(ml, 16));
    ml = fmaxf(ml, __shfl_xor(ml, 32));

    if (!__all(ml - mrow <= 11.0f)) {
      const float mn2 = fmaxf(mrow, ml);
      const float a   = fexp2(mrow - mn2);
      float al[4];
#pragma unroll
      for (int r = 0; r < 4; r++) al[r] = __shfl(a, quad * 4 + r);
#pragma unroll
      for (int i = 0; i < 4; i++)
#pragma unroll
        for (int r = 0; r < 4; r++) o[i][r] *= al[r];
      lrow *= a;
      mrow = mn2;
    }
    const float mn = mrow;

    float sl = 0.f;
    h4 pf[4];
#pragma unroll
    for (int ct = 0; ct < 4; ct++) {
      const float e0 = fexp2(st[ct][0] - mn);
      const float e1 = fexp2(st[ct][1] - mn);
      const float e2 = fexp2(st[ct][2] - mn);
      const float e3 = fexp2(st[ct][3] - mn);
      sl += (e0 + e1) + (e2 + e3);
      pf[ct] = (h4){(_Float16)e0, (_Float16)e1, (_Float16)e2, (_Float16)e3};
    }
    sl += __shfl_xor(sl, 16);
    sl += __shfl_xor(sl, 32);
    lrow += sl;

#pragma unroll
    for (int ctd = 0; ctd < 4; ctd++) {
      const unsigned short* vrow = Vc + (ctd * 16 + m16) * LD_ + quad * 16;
      V8 va, vb;
      va.u = *(const uint4*)(vrow);
      vb.u = *(const uint4*)(vrow + 8);
      o[ctd] = __builtin_amdgcn_mfma_f32_16x16x16f16(pf[0], va.f[0], o[ctd], 0, 0, 0);
      o[ctd] = __builtin_amdgcn_mfma_f32_16x16x16f16(pf[1], va.f[1], o[ctd], 0, 0, 0);
      o[ctd] = __builtin_amdgcn_mfma_f32_16x16x16f16(pf[2], vb.f[0], o[ctd], 0, 0, 0);
      o[ctd] = __builtin_amdgcn_mfma_f32_16x16x16f16(pf[3], vb.f[1], o[ctd], 0, 0, 0);
    }

    if (more) {
      __syncthreads();
      unsigned short* kd = &Kt[cur ^ 1][0] + sr * LD_ + sc;
      unsigned short* vd = &Vt[cur ^ 1][0] + sr * LD_ + vdoff;
      *(uint4*)(kd) = kr;
      *(uint2*)(vd)      = make_uint2(vr.x, vr.y);
      *(uint2*)(vd + 16) = make_uint2(vr.z, vr.w);
      __syncthreads();
    }
  }

  float linv[4];
#pragma unroll
  for (int r = 0; r < 4; r++) linv[r] = 1.f / __shfl(lrow, quad * 4 + r);

#pragma unroll
  for (int r = 0; r < 4; r++) {
    const int tq = q0 + quad * 4 + r;
    unsigned short* dst = comb + ((size_t)b * T_ + tq) * E_ + h * D_;
    dst[m16]      = f2h(o[0][r] * linv[r]);
    dst[16 + m16] = f2h(o[1][r] * linv[r]);
    dst[32 + m16] = f2h(o[2][r] * linv[r]);
    dst[48 + m16] = f2h(o[3][r] * linv[r]);
  }
}

// ---------------------------------------------------------------------------
// Kernel 3: out = comb @ Wo + x, coalesced LDS staging.
// grid=(B*T/128, E/64), block=256 (4 waves). Block: 128 n x 64 j.
// ---------------------------------------------------------------------------
__global__ __launch_bounds__(256) void out_mfma(
    const unsigned short* __restrict__ comb, const unsigned short* __restrict__ wot,
    const float* __restrict__ x, float* __restrict__ out)
{
  __shared__ unsigned short cs[128 * LD_];   // [n][e]
  __shared__ unsigned short wsb[64 * LD_];   // [j][e]

  const int tid = threadIdx.x;
  const int w = tid >> 6, lane = tid & 63;
  const int m16 = lane & 15, quad = lane >> 4;
  const int n0 = blockIdx.x * 128;
  const int j0 = blockIdx.y * 64;

  const int sr = tid >> 3;          // 0..31
  const int sc = (tid & 7) * 8;     // 0,8,...,56

  f32x4 acc[2][4];
#pragma unroll
  for (int rt = 0; rt < 2; rt++)
#pragma unroll
    for (int ct = 0; ct < 4; ct++) acc[rt][ct] = (f32x4){0.f, 0.f, 0.f, 0.f};

  for (int e0 = 0; e0 < E_; e0 += 64) {
    __syncthreads();
#pragma unroll
    for (int it = 0; it < 4; it++) {
      const int row = it * 32 + sr;
      *(uint4*)(cs + row * LD_ + sc) =
          *(const uint4*)(comb + (size_t)(n0 + row) * E_ + e0 + sc);
    }
#pragma unroll
    for (int it = 0; it < 2; it++) {
      const int row = it * 32 + sr;
      *(uint4*)(wsb + row * LD_ + sc) =
          *(const uint4*)(wot + (size_t)(j0 + row) * E_ + e0 + sc);
    }
    __syncthreads();

#pragma unroll
    for (int kk = 0; kk < 64; kk += 32) {
      U4 a0, a1, bf[4];
      a0.u = *(const uint4*)(cs + (w * 32 + m16) * LD_ + kk + quad * 8);
      a1.u = *(const uint4*)(cs + (w * 32 + 16 + m16) * LD_ + kk + quad * 8);
#pragma unroll
      for (int ct = 0; ct < 4; ct++)
        bf[ct].u = *(const uint4*)(wsb + (ct * 16 + m16) * LD_ + kk + quad * 8);
#pragma unroll
      for (int ct = 0; ct < 4; ct++) {
        acc[0][ct] = __builtin_amdgcn_mfma_f32_16x16x32_f16(a0.h, bf[ct].h, acc[0][ct], 0, 0, 0);
        acc[1][ct] = __builtin_amdgcn_mfma_f32_16x16x32_f16(a1.h, bf[ct].h, acc[1][ct], 0, 0, 0);
      }
    }
  }

  const int nw = n0 + w * 32;
#pragma unroll
  for (int rt = 0; rt < 2; rt++)
#pragma unroll
    for (int r = 0; r < 4; r++) {
      const int n = nw + rt * 16 + quad * 4 + r;
      const float* xr = x + (size_t)n * E_ + j0;
      float* orow = out + (size_t)n * E_ + j0;
#pragma unroll
      for (int ct = 0; ct < 4; ct++) {
        const int j = ct * 16 + m16;
        orow[j] = acc[rt][ct][r] + xr[j];
      }
    }
}

// ---------------------------------------------------------------------------
extern "C" void kernel_launch(void* const* d_in, const int* in_sizes, int n_in,
                              void* d_out, int out_size, void* d_ws, size_t ws_size,
                              hipStream_t stream) {
  (void)in_sizes; (void)n_in; (void)out_size; (void)ws_size;

  const float* x  = (const float*)d_in[0];
  const float* Wq = (const float*)d_in[1];
  const float* Wk = (const float*)d_in[2];
  const float* Wv = (const float*)d_in[3];
  const float* Wo = (const float*)d_in[4];
  float* out = (float*)d_out;

  unsigned short* ws0  = (unsigned short*)d_ws;
  unsigned short* xh   = ws0;                    // 4M elems (aliases comb)
  unsigned short* wt   = ws0 + 4194304;          // 3M
  unsigned short* wot  = ws0 + 7340032;          // 1M
  unsigned short* qh   = ws0 + 8388608;          // 4M
  unsigned short* kh   = ws0 + 12582912;         // 4M
  unsigned short* vth  = ws0 + 16777216;         // 32*64*2176 = 4.46M (padded)
  unsigned short* comb = xh;                     // alias: xh dead after qkv

  prep_fused<<<dim3(4096 + 768 + 256), dim3(256), 0, stream>>>(
      x, xh, Wq, Wk, Wv, wt, Wo, wot);

  qkv_mfma<<<dim3(B_ * T_ / 256, H_, 3), dim3(256), 0, stream>>>(xh, wt, qh, kh, vth);

  attn_kernel<<<dim3(B_ * H_ * (T_ / 128)), dim3(512), 0, stream>>>(qh, kh, vth, comb);

  out_mfma<<<dim3(B_ * T_ / 128, E_ / 64), dim3(256), 0, stream>>>(comb, wot, x, out);
}

// Round 15
// 198.242 us; speedup vs baseline: 1.1087x; 1.0513x over previous
//
#include <hip/hip_runtime.h>
#include <hip/hip_bf16.h>

// MultiAttentionHead: B=2, T=2048, E=1024, H=16, D=64
// Inputs (fp32): x[B,T,E], Wq[H,E,D], Wk[H,E,D], Wv[H,E,D], Wo[E,E]
// Output (fp32): combined @ Wo + x   [B,T,E]
//
// r11: attn softmax fully in-register (swapped QK^T; exp'd values feed PV).
// r12-r14: KV=128 spilled -> keep per-wave state small, static indices.
// r15: XCD-bijective swizzle (FETCH 70->12MB, L2-resident) + defer-max.
// r17: 8-wave attn + permuted V (PV b128 conflict-free) + exp2 softmax.
//      attn 66us. BEST attn config.
// r18/r19: qkv restructures neutral-to-worse; R8's 8-wave qkv = best total
//      (205.5). r22: 4-wave attn regressed (76us). r23: prep fusion neutral
//      -> launch overhead negligible; non-attn time is kernel-resident.
// r24/r25 (this round; r24 bench was an infra failure, resubmitted
//      unchanged): best-of assembly + attn VALU trims:
//      (a) qkv reverted to R8 8-wave version (205.5us config),
//      (b) cvt_pkrtz P-packing (8 ops vs 16 cvt + 8 pack per tile),
//      (c) lazy max-reduce: __all defer-check with LANE-LOCAL max
//          (equivalent condition; true reduced max computed only in the
//          rare trigger path before rescaling — numerics identical).

#define B_ 2
#define T_ 2048
#define E_ 1024
#define H_ 16
#define D_ 64
#define VTS_ 2176   // padded vt leading dim (elements)
#define LD_ 72      // LDS tile row stride (elements; 64 + 8, keeps 16B align)

typedef _Float16 h8 __attribute__((ext_vector_type(8)));
typedef _Float16 h4 __attribute__((ext_vector_type(4)));
typedef __fp16  pk2 __attribute__((ext_vector_type(2)));
typedef float f32x4 __attribute__((ext_vector_type(4)));

union U4 { uint4 u; h8 h; };
union V8 { uint4 u; h4 f[2]; };   // 16 bytes = 8 halves = 2 PV B-fragments
union PK4 { pk2 p[2]; h4 h; };    // 2x cvt_pkrtz -> one PV A-fragment

__device__ __forceinline__ float h2f(unsigned short s) {
  _Float16 h;
  __builtin_memcpy(&h, &s, 2);
  return (float)h;
}

__device__ __forceinline__ unsigned short f2h(float f) {
  _Float16 h = (_Float16)f;
  unsigned short s;
  __builtin_memcpy(&s, &h, 2);
  return s;
}

// exp2 via v_exp_f32 when available; mathematically-identical fallback.
__device__ __forceinline__ float fexp2(float x) {
#if __has_builtin(__builtin_amdgcn_exp2f)
  return __builtin_amdgcn_exp2f(x);
#else
  return __expf(x * 0.6931471805599453f);
#endif
}

// ---------------------------------------------------------------------------
// Fused prep: grid = 5120 flat, block = 256.
//   bid <  4096 : x fp32 -> fp16 (1024 elems/block)
//   4096..4863  : Wq/Wk/Wv [h][e][d] -> wt [p][h][d][e] fp16 (Wq pre-scaled
//                 by 0.125*log2e; softmax runs in exp2 domain)
//   4864..5119  : Wo [e][j] -> wot [j][e] fp16
// ---------------------------------------------------------------------------
__global__ __launch_bounds__(256) void prep_fused(
    const float* __restrict__ x,  unsigned short* __restrict__ xh,
    const float* __restrict__ Wq, const float* __restrict__ Wk,
    const float* __restrict__ Wv, unsigned short* __restrict__ wt,
    const float* __restrict__ Wo, unsigned short* __restrict__ wot)
{
  __shared__ float ts[64][65];
  const int bid = blockIdx.x;
  const int tid = threadIdx.x;

  if (bid < 4096) {                    // ---- cvt_x ----
    const size_t i = ((size_t)bid * 256 + tid) * 4;
    const float4 f = *(const float4*)(x + i);
    ushort4 pk;
    pk.x = f2h(f.x); pk.y = f2h(f.y); pk.z = f2h(f.z); pk.w = f2h(f.w);
    *(ushort4*)(xh + i) = pk;
    return;
  }

  const int lr = tid >> 4, lc = (tid & 15) * 4;

  if (bid < 4096 + 768) {              // ---- tconv_w ----
    const int idx = bid - 4096;        // 768 = 16 e-tiles x 16 h x 3 p
    const int et = idx & 15, h = (idx >> 4) & 15, p = idx >> 8;
    const float* src = ((p == 0) ? Wq : (p == 1) ? Wk : Wv) + (size_t)h * E_ * D_;
    unsigned short* dst = wt + (size_t)(p * H_ + h) * D_ * E_;
    const float scl = (p == 0) ? 0.18033688011112042f : 1.0f;  // 0.125*log2(e)
    const int r0 = et * 64;            // e-tile
#pragma unroll
    for (int it = 0; it < 4; it++) {
      const float4 f = *(const float4*)(src + (size_t)(r0 + lr + it * 16) * D_ + lc);
      ts[lr + it * 16][lc] = f.x * scl; ts[lr + it * 16][lc + 1] = f.y * scl;
      ts[lr + it * 16][lc + 2] = f.z * scl; ts[lr + it * 16][lc + 3] = f.w * scl;
    }
    __syncthreads();
#pragma unroll
    for (int it = 0; it < 4; it++) {
      const int dr = lr + it * 16;     // d
      ushort4 pk;
      pk.x = f2h(ts[lc + 0][dr]); pk.y = f2h(ts[lc + 1][dr]);
      pk.z = f2h(ts[lc + 2][dr]); pk.w = f2h(ts[lc + 3][dr]);
      *(ushort4*)(dst + (size_t)dr * E_ + r0 + lc) = pk;
    }
    return;
  }

  {                                    // ---- tconv_wo ----
    const int idx = bid - 4096 - 768;  // 256 = 16 x 16
    const int r0 = (idx & 15) * 64;    // e-tile
    const int c0 = (idx >> 4) * 64;    // j-tile
#pragma unroll
    for (int it = 0; it < 4; it++) {
      const float4 f = *(const float4*)(Wo + (size_t)(r0 + lr + it * 16) * E_ + c0 + lc);
      ts[lr + it * 16][lc] = f.x; ts[lr + it * 16][lc + 1] = f.y;
      ts[lr + it * 16][lc + 2] = f.z; ts[lr + it * 16][lc + 3] = f.w;
    }
    __syncthreads();
#pragma unroll
    for (int it = 0; it < 4; it++) {
      const int dr = lr + it * 16;     // j within tile
      ushort4 pk;
      pk.x = f2h(ts[lc + 0][dr]); pk.y = f2h(ts[lc + 1][dr]);
      pk.z = f2h(ts[lc + 2][dr]); pk.w = f2h(ts[lc + 3][dr]);
      *(ushort4*)(wot + (size_t)(c0 + dr) * E_ + r0 + lc) = pk;
    }
  }
}

// ---------------------------------------------------------------------------
// Kernel 1: QKV projections via MFMA (R8 8-wave version — best-total config).
// grid=(B*T/256, H, 3), block=512 (8 waves). Block: 256 tokens x 64 outs.
// ---------------------------------------------------------------------------
__global__ __launch_bounds__(512) void qkv_mfma(
    const unsigned short* __restrict__ xh, const unsigned short* __restrict__ wt,
    unsigned short* __restrict__ qo, unsigned short* __restrict__ ko,
    unsigned short* __restrict__ vo)
{
  __shared__ unsigned short xs[256 * LD_];   // [token][e]; epilogue: repack
  __shared__ unsigned short wsb[64 * LD_];   // [d][e]

  const int tid = threadIdx.x;
  const int w = tid >> 6, lane = tid & 63;
  const int m16 = lane & 15, quad = lane >> 4;
  const int h = blockIdx.y, p = blockIdx.z;
  const int n0 = blockIdx.x * 256;           // block token base
  const unsigned short* wb = wt + (size_t)(p * H_ + h) * D_ * E_;

  const int sr = tid >> 3;          // 0..63
  const int sc = (tid & 7) * 8;     // 0,8,...,56

  f32x4 acc[2][4];
#pragma unroll
  for (int rt = 0; rt < 2; rt++)
#pragma unroll
    for (int ct = 0; ct < 4; ct++) acc[rt][ct] = (f32x4){0.f, 0.f, 0.f, 0.f};

  for (int e0 = 0; e0 < E_; e0 += 64) {
    __syncthreads();
#pragma unroll
    for (int it = 0; it < 4; it++) {
      const int row = it * 64 + sr;
      *(uint4*)(xs + row * LD_ + sc) =
          *(const uint4*)(xh + (size_t)(n0 + row) * E_ + e0 + sc);
    }
    *(uint4*)(wsb + sr * LD_ + sc) =
        *(const uint4*)(wb + (size_t)sr * E_ + e0 + sc);
    __syncthreads();

#pragma unroll
    for (int kk = 0; kk < 64; kk += 32) {
      U4 a0, a1, bf[4];
      a0.u = *(const uint4*)(xs + (w * 32 + m16) * LD_ + kk + quad * 8);
      a1.u = *(const uint4*)(xs + (w * 32 + 16 + m16) * LD_ + kk + quad * 8);
#pragma unroll
      for (int ct = 0; ct < 4; ct++)
        bf[ct].u = *(const uint4*)(wsb + (ct * 16 + m16) * LD_ + kk + quad * 8);
#pragma unroll
      for (int ct = 0; ct < 4; ct++) {
        acc[0][ct] = __builtin_amdgcn_mfma_f32_16x16x32_f16(a0.h, bf[ct].h, acc[0][ct], 0, 0, 0);
        acc[1][ct] = __builtin_amdgcn_mfma_f32_16x16x32_f16(a1.h, bf[ct].h, acc[1][ct], 0, 0, 0);
      }
    }
  }

  const int nw = n0 + w * 32;               // wave token base
  const int b  = n0 >> 11;                  // batch (256 | 2048, never straddles)
  const int t0 = nw & (T_ - 1);
  const size_t bh = (size_t)(b * H_ + h);

  if (p == 2) {
#pragma unroll
    for (int rt = 0; rt < 2; rt++)
#pragma unroll
      for (int ct = 0; ct < 4; ct++) {
        const int d = ct * 16 + m16;
        const int t = t0 + rt * 16 + quad * 4;
        ushort4 pk;
        pk.x = f2h(acc[rt][ct][0]); pk.y = f2h(acc[rt][ct][1]);
        pk.z = f2h(acc[rt][ct][2]); pk.w = f2h(acc[rt][ct][3]);
        *(ushort4*)(vo + (bh * D_ + d) * (size_t)VTS_ + t) = pk;
      }
  } else {
    unsigned short* outp = (p == 0) ? qo : ko;
    __syncthreads();                        // xs reads of last e0 done
    unsigned short* Cw = xs + w * (32 * 72);  // reuse xs: 8*32*72 = 18432 ✓
#pragma unroll
    for (int rt = 0; rt < 2; rt++)
#pragma unroll
      for (int ct = 0; ct < 4; ct++)
#pragma unroll
        for (int r = 0; r < 4; r++)
          Cw[(rt * 16 + quad * 4 + r) * 72 + ct * 16 + m16] = f2h(acc[rt][ct][r]);
    const int row = lane >> 1;
    const int half = (lane & 1) * 32;
    const uint4 d0 = *(const uint4*)(Cw + row * 72 + half);
    const uint4 d1 = *(const uint4*)(Cw + row * 72 + half + 8);
    const uint4 d2 = *(const uint4*)(Cw + row * 72 + half + 16);
    const uint4 d3 = *(const uint4*)(Cw + row * 72 + half + 24);
    unsigned short* dst = outp + (bh * T_ + t0 + row) * D_ + half;
    *(uint4*)(dst)      = d0;
    *(uint4*)(dst + 8)  = d1;
    *(uint4*)(dst + 16) = d2;
    *(uint4*)(dst + 24) = d3;
  }
}

// ---------------------------------------------------------------------------
// Kernel 2: MFMA flash attention (r17 8-wave + r24 VALU trims).
// grid = 512 flat (XCD-swizzled), block = 512 (8 waves = 8 Q-tiles of 16).
// KV tile = 64, LDS double-buffered; permuted V (PV b128 conflict-free);
// exp2 softmax (scale folded into Wq); defer-max THR=11 bits (lazy reduce);
// cvt_pkrtz P-packing.
// ---------------------------------------------------------------------------
__global__ __launch_bounds__(512) void attn_kernel(
    const unsigned short* __restrict__ q, const unsigned short* __restrict__ k,
    const unsigned short* __restrict__ vt, unsigned short* __restrict__ comb)
{
  __shared__ unsigned short Kt[2][64 * LD_];   // [key][d]
  __shared__ unsigned short Vt[2][64 * LD_];   // [d][key-permuted]

  const int tid  = threadIdx.x;
  const int w    = tid >> 6;          // 0..7
  const int lane = tid & 63;
  const int m16  = lane & 15;
  const int quad = lane >> 4;

  const int flat = blockIdx.x;                   // 0..511
  const int swz  = (flat & 7) * 64 + (flat >> 3);
  const int xq   = swz & 15;
  const int h    = (swz >> 4) & 15;
  const int b    = swz >> 8;

  const size_t bh = (size_t)(b * H_ + h);
  const int q0 = xq * 128 + w * 16;

  U4 aQ0, aQ1;
  {
    const unsigned short* qrow = q + (bh * T_ + q0 + m16) * (size_t)D_;
    aQ0.u = *(const uint4*)(qrow + quad * 8);
    aQ1.u = *(const uint4*)(qrow + 32 + quad * 8);
  }

  f32x4 o[4];
#pragma unroll
  for (int i = 0; i < 4; i++) o[i] = (f32x4){0.f, 0.f, 0.f, 0.f};
  float mrow = -1e30f;   // running max (log2 units) of q-row m16
  float lrow = 0.f;      // running denom of q-row m16

  const int sr = tid >> 3;          // 0..63
  const int sc = (tid & 7) * 8;     // 0,8,...,56
  const int vdoff = ((sc >> 2) & 3) * 16 + (sc >> 4) * 4;

  const unsigned short* kp = k  + bh * (size_t)(T_ * D_)   + (size_t)sr * D_ + sc;
  const unsigned short* vp = vt + bh * (size_t)(D_ * VTS_) + (size_t)sr * VTS_ + sc;

  uint4 kr, vr;
  kr = *(const uint4*)(kp);
  vr = *(const uint4*)(vp);
  kp += 64 * D_; vp += 64;
  {
    unsigned short* kd = &Kt[0][0] + sr * LD_ + sc;
    unsigned short* vd = &Vt[0][0] + sr * LD_ + vdoff;
    *(uint4*)(kd) = kr;
    *(uint2*)(vd)      = make_uint2(vr.x, vr.y);
    *(uint2*)(vd + 16) = make_uint2(vr.z, vr.w);
  }
  __syncthreads();

  const int NT = T_ / 64;
  for (int t = 0; t < NT; t++) {
    const int cur = t & 1;
    const unsigned short* Kc = &Kt[cur][0];
    const unsigned short* Vc = &Vt[cur][0];
    const bool more = (t + 1 < NT);
    if (more) {   // issue next tile a full compute early
      kr = *(const uint4*)(kp);
      vr = *(const uint4*)(vp);
      kp += 64 * D_; vp += 64;
    }

    f32x4 st[4];
#pragma unroll
    for (int ct = 0; ct < 4; ct++) {
      U4 kf0, kf1;
      kf0.u = *(const uint4*)(Kc + (ct * 16 + m16) * LD_ + quad * 8);
      kf1.u = *(const uint4*)(Kc + (ct * 16 + m16) * LD_ + 32 + quad * 8);
      f32x4 z = {0.f, 0.f, 0.f, 0.f};
      z = __builtin_amdgcn_mfma_f32_16x16x32_f16(kf0.h, aQ0.h, z, 0, 0, 0);
      z = __builtin_amdgcn_mfma_f32_16x16x32_f16(kf1.h, aQ1.h, z, 0, 0, 0);
      st[ct] = z;
    }

    // lane-local max over this lane's 16 keys; __all over lanes covers the
    // full row set, so the defer check is EQUIVALENT to using true row max.
    const float m0 = fmaxf(fmaxf(st[0][0], st[0][1]), fmaxf(st[0][2], st[0][3]));
    const float m1 = fmaxf(fmaxf(st[1][0], st[1][1]), fmaxf(st[1][2], st[1][3]));
    const float m2 = fmaxf(fmaxf(st[2][0], st[2][1]), fmaxf(st[2][2], st[2][3]));
    const float m3 = fmaxf(fmaxf(st[3][0], st[3][1]), fmaxf(st[3][2], st[3][3]));
    float ml = fmaxf(fmaxf(m0, m1), fmaxf(m2, m3));

    if (!__all(ml - mrow <= 11.0f)) {   // rare: reduce + rescale
      ml = fmaxf(ml, __shfl_xor(ml, 16));
      ml = fmaxf(ml, __shfl_xor(ml, 32));
      const float mn2 = fmaxf(mrow, ml);
      const float a   = fexp2(mrow - mn2);
      float al[4];
#pragma unroll
      for (int r = 0; r < 4; r++) al[r] = __shfl(a, quad * 4 + r);
#pragma unroll
      for (int i = 0; i < 4; i++)
#pragma unroll
        for (int r = 0; r < 4; r++) o[i][r] *= al[r];
      lrow *= a;
      mrow = mn2;
    }
    const float mn = mrow;

    float sl = 0.f;
    h4 pf[4];
#pragma unroll
    for (int ct = 0; ct < 4; ct++) {
      const float e0 = fexp2(st[ct][0] - mn);
      const float e1 = fexp2(st[ct][1] - mn);
      const float e2 = fexp2(st[ct][2] - mn);
      const float e3 = fexp2(st[ct][3] - mn);
      sl += (e0 + e1) + (e2 + e3);
      PK4 u;
      u.p[0] = __builtin_amdgcn_cvt_pkrtz(e0, e1);
      u.p[1] = __builtin_amdgcn_cvt_pkrtz(e2, e3);
      pf[ct] = u.h;
    }
    sl += __shfl_xor(sl, 16);
    sl += __shfl_xor(sl, 32);
    lrow += sl;

#pragma unroll
    for (int ctd = 0; ctd < 4; ctd++) {
      const unsigned short* vrow = Vc + (ctd * 16 + m16) * LD_ + quad * 16;
      V8 va, vb;
      va.u = *(const uint4*)(vrow);
      vb.u = *(const uint4*)(vrow + 8);
      o[ctd] = __builtin_amdgcn_mfma_f32_16x16x16f16(pf[0], va.f[0], o[ctd], 0, 0, 0);
      o[ctd] = __builtin_amdgcn_mfma_f32_16x16x16f16(pf[1], va.f[1], o[ctd], 0, 0, 0);
      o[ctd] = __builtin_amdgcn_mfma_f32_16x16x16f16(pf[2], vb.f[0], o[ctd], 0, 0, 0);
      o[ctd] = __builtin_amdgcn_mfma_f32_16x16x16f16(pf[3], vb.f[1], o[ctd], 0, 0, 0);
    }

    if (more) {
      __syncthreads();
      unsigned short* kd = &Kt[cur ^ 1][0] + sr * LD_ + sc;
      unsigned short* vd = &Vt[cur ^ 1][0] + sr * LD_ + vdoff;
      *(uint4*)(kd) = kr;
      *(uint2*)(vd)      = make_uint2(vr.x, vr.y);
      *(uint2*)(vd + 16) = make_uint2(vr.z, vr.w);
      __syncthreads();
    }
  }

  float linv[4];
#pragma unroll
  for (int r = 0; r < 4; r++) linv[r] = 1.f / __shfl(lrow, quad * 4 + r);

#pragma unroll
  for (int r = 0; r < 4; r++) {
    const int tq = q0 + quad * 4 + r;
    unsigned short* dst = comb + ((size_t)b * T_ + tq) * E_ + h * D_;
    dst[m16]      = f2h(o[0][r] * linv[r]);
    dst[16 + m16] = f2h(o[1][r] * linv[r]);
    dst[32 + m16] = f2h(o[2][r] * linv[r]);
    dst[48 + m16] = f2h(o[3][r] * linv[r]);
  }
}

// ---------------------------------------------------------------------------
// Kernel 3: out = comb @ Wo + x, coalesced LDS staging.
// grid=(B*T/128, E/64), block=256 (4 waves). Block: 128 n x 64 j.
// ---------------------------------------------------------------------------
__global__ __launch_bounds__(256) void out_mfma(
    const unsigned short* __restrict__ comb, const unsigned short* __restrict__ wot,
    const float* __restrict__ x, float* __restrict__ out)
{
  __shared__ unsigned short cs[128 * LD_];   // [n][e]
  __shared__ unsigned short wsb[64 * LD_];   // [j][e]

  const int tid = threadIdx.x;
  const int w = tid >> 6, lane = tid & 63;
  const int m16 = lane & 15, quad = lane >> 4;
  const int n0 = blockIdx.x * 128;
  const int j0 = blockIdx.y * 64;

  const int sr = tid >> 3;          // 0..31
  const int sc = (tid & 7) * 8;     // 0,8,...,56

  f32x4 acc[2][4];
#pragma unroll
  for (int rt = 0; rt < 2; rt++)
#pragma unroll
    for (int ct = 0; ct < 4; ct++) acc[rt][ct] = (f32x4){0.f, 0.f, 0.f, 0.f};

  for (int e0 = 0; e0 < E_; e0 += 64) {
    __syncthreads();
#pragma unroll
    for (int it = 0; it < 4; it++) {
      const int row = it * 32 + sr;
      *(uint4*)(cs + row * LD_ + sc) =
          *(const uint4*)(comb + (size_t)(n0 + row) * E_ + e0 + sc);
    }
#pragma unroll
    for (int it = 0; it < 2; it++) {
      const int row = it * 32 + sr;
      *(uint4*)(wsb + row * LD_ + sc) =
          *(const uint4*)(wot + (size_t)(j0 + row) * E_ + e0 + sc);
    }
    __syncthreads();

#pragma unroll
    for (int kk = 0; kk < 64; kk += 32) {
      U4 a0, a1, bf[4];
      a0.u = *(const uint4*)(cs + (w * 32 + m16) * LD_ + kk + quad * 8);
      a1.u = *(const uint4*)(cs + (w * 32 + 16 + m16) * LD_ + kk + quad * 8);
#pragma unroll
      for (int ct = 0; ct < 4; ct++)
        bf[ct].u = *(const uint4*)(wsb + (ct * 16 + m16) * LD_ + kk + quad * 8);
#pragma unroll
      for (int ct = 0; ct < 4; ct++) {
        acc[0][ct] = __builtin_amdgcn_mfma_f32_16x16x32_f16(a0.h, bf[ct].h, acc[0][ct], 0, 0, 0);
        acc[1][ct] = __builtin_amdgcn_mfma_f32_16x16x32_f16(a1.h, bf[ct].h, acc[1][ct], 0, 0, 0);
      }
    }
  }

  const int nw = n0 + w * 32;
#pragma unroll
  for (int rt = 0; rt < 2; rt++)
#pragma unroll
    for (int r = 0; r < 4; r++) {
      const int n = nw + rt * 16 + quad * 4 + r;
      const float* xr = x + (size_t)n * E_ + j0;
      float* orow = out + (size_t)n * E_ + j0;
#pragma unroll
      for (int ct = 0; ct < 4; ct++) {
        const int j = ct * 16 + m16;
        orow[j] = acc[rt][ct][r] + xr[j];
      }
    }
}

// ---------------------------------------------------------------------------
extern "C" void kernel_launch(void* const* d_in, const int* in_sizes, int n_in,
                              void* d_out, int out_size, void* d_ws, size_t ws_size,
                              hipStream_t stream) {
  (void)in_sizes; (void)n_in; (void)out_size; (void)ws_size;

  const float* x  = (const float*)d_in[0];
  const float* Wq = (const float*)d_in[1];
  const float* Wk = (const float*)d_in[2];
  const float* Wv = (const float*)d_in[3];
  const float* Wo = (const float*)d_in[4];
  float* out = (float*)d_out;

  unsigned short* ws0  = (unsigned short*)d_ws;
  unsigned short* xh   = ws0;                    // 4M elems (aliases comb)
  unsigned short* wt   = ws0 + 4194304;          // 3M
  unsigned short* wot  = ws0 + 7340032;          // 1M
  unsigned short* qh   = ws0 + 8388608;          // 4M
  unsigned short* kh   = ws0 + 12582912;         // 4M
  unsigned short* vth  = ws0 + 16777216;         // 32*64*2176 = 4.46M (padded)
  unsigned short* comb = xh;                     // alias: xh dead after qkv

  prep_fused<<<dim3(4096 + 768 + 256), dim3(256), 0, stream>>>(
      x, xh, Wq, Wk, Wv, wt, Wo, wot);

  qkv_mfma<<<dim3(B_ * T_ / 256, H_, 3), dim3(512), 0, stream>>>(xh, wt, qh, kh, vth);

  attn_kernel<<<dim3(B_ * H_ * (T_ / 128)), dim3(512), 0, stream>>>(qh, kh, vth, comb);

  out_mfma<<<dim3(B_ * T_ / 128, E_ / 64), dim3(256), 0, stream>>>(comb, wot, x, out);
}